// Round 3
// baseline (427.065 us; speedup 1.0000x reference)
//
#include <hip/hip_runtime.h>
#include <hip/hip_fp16.h>

static constexpr int HH = 2048;
static constexpr int WW = 2048;
static constexpr int PADT = 24;   // top/bottom pad rows
static constexpr int PADL = 8;    // left/right pad cols (need 4, use 8 for alignment)
static constexpr int SW   = WW + 2 * PADL;          // 2064 floats
static constexpr int PROWS = HH + 2 * PADT;         // 2096 rows
static constexpr size_t PadElems = (size_t)PROWS * SW;
static constexpr int ROWS = 8;    // output rows per thread in filter kernels

// segment tables for +10 deg: lval(d)=round(d*tan(10deg)), runs of constant offset
__device__ constexpr int CS[9] = {-24,-19,-14,-8,-2, 3, 9,15,20};
__device__ constexpr int CE[9] = {-20,-15, -9,-3, 2, 8,14,19,24};
__device__ constexpr int CO[9] = { -4, -3, -2,-1, 0, 1, 2, 3, 4};

// ---- one slanted segment: vertical run [SS,EE] at col offset OO ----
template<int SS, int EE, int OO>
__device__ __forceinline__ void seg_one(const float* __restrict__ tp, int h0, int w,
                                        float* __restrict__ acc) {
  constexpr int L = EE - SS + 1;        // 5 or 6
  const float* p = tp + (h0 + SS + PADT) * SW + (w + OO + PADL);
  float ring[L - 1];
  float s = 0.0f;
#pragma unroll
  for (int k = 0; k < L - 1; ++k) { float v = p[k * SW]; ring[k] = v; s += v; }
#pragma unroll
  for (int r = 0; r < ROWS; ++r) {
    float v = p[(L - 1 + r) * SW];
    acc[r] += s + v;
    s += v - ring[r % (L - 1)];
    ring[r % (L - 1)] = v;
  }
}

template<int SGN>   // +1 => +10deg, -1 => -10deg
__device__ __forceinline__ void filt_slant(const float* __restrict__ tp, int h0, int w,
                                           float* __restrict__ acc) {
  seg_one<-24, -20, -4 * SGN>(tp, h0, w, acc);
  seg_one<-19, -15, -3 * SGN>(tp, h0, w, acc);
  seg_one<-14,  -9, -2 * SGN>(tp, h0, w, acc);
  seg_one< -8,  -3, -1 * SGN>(tp, h0, w, acc);
  seg_one< -2,   2,  0      >(tp, h0, w, acc);
  seg_one<  3,   8,  1 * SGN>(tp, h0, w, acc);
  seg_one<  9,  14,  2 * SGN>(tp, h0, w, acc);
  seg_one< 15,  19,  3 * SGN>(tp, h0, w, acc);
  seg_one< 20,  24,  4 * SGN>(tp, h0, w, acc);
}

// A: 0 => -10deg, 1 => 0deg, 2 => +10deg
template<int A>
__device__ __forceinline__ void filtN(const float* __restrict__ tp, int h0, int w,
                                      float* __restrict__ acc) {
#pragma unroll
  for (int r = 0; r < ROWS; ++r) acc[r] = 0.0f;
  if constexpr (A == 1) {
    const float* p = tp + (h0 - 24 + PADT) * SW + (w + PADL);
    float s = 0.0f;
#pragma unroll
    for (int k = 0; k < 48; ++k) s += p[k * SW];
#pragma unroll
    for (int r = 0; r < ROWS; ++r) {
      float vin = p[(48 + r) * SW];
      acc[r] = s + vin;
      s += vin - p[r * SW];
    }
  } else if constexpr (A == 0) {
    filt_slant<-1>(tp, h0, w, acc);
  } else {
    filt_slant<+1>(tp, h0, w, acc);
  }
}

// analytic 1/N (N = in-bounds tap count of zero-padded conv)
template<int A>
__device__ __forceinline__ float rcpcnt(int h, int w) {
  if (h >= 24 && h <= 2023 && w >= 4 && w <= 2043) return 1.0f / 49.0f;
  int cnt = 0;
  if constexpr (A == 1) {
    cnt = min(h + 24, HH - 1) - max(h - 24, 0) + 1;
  } else {
    const int sgn = (A == 0) ? -1 : 1;
#pragma unroll
    for (int j = 0; j < 9; ++j) {
      const int ww = w + sgn * CO[j];
      const int ov = min(h + CE[j], HH - 1) - max(h + CS[j], 0) + 1;
      if (ww >= 0 && ww < WW && ov > 0) cnt += ov;
    }
  }
  return 1.0f / (float)cnt;
}

// ---- pass A: bp = filt(tp)/N ----
template<int A>
__global__ __launch_bounds__(256, 6) void passA(const float* __restrict__ tp,
                                                float* __restrict__ bp) {
  const int w  = blockIdx.x * 256 + threadIdx.x;
  const int h0 = blockIdx.y * ROWS;
  float acc[ROWS];
  filtN<A>(tp, h0, w, acc);
#pragma unroll
  for (int r = 0; r < ROWS; ++r) {
    const int h = h0 + r;
    bp[(h + PADT) * SW + (w + PADL)] = acc[r] * rcpcnt<A>(h, w);
  }
}

// ---- pass B: res = xcin + filt(bp)/N; mid: {xcout=res, tp=y-res}; final: dh=half(res-X) ----
template<int A, bool FINAL>
__global__ __launch_bounds__(256, 6) void passB(const float* __restrict__ bp,
                                                const float* __restrict__ xcin,
                                                const float* __restrict__ aux, // y (mid) or X (final)
                                                float* __restrict__ xcout,
                                                float* __restrict__ tp,
                                                __half* __restrict__ dh) {
  const int w  = blockIdx.x * 256 + threadIdx.x;
  const int h0 = blockIdx.y * ROWS;
  float acc[ROWS];
  filtN<A>(bp, h0, w, acc);
#pragma unroll
  for (int r = 0; r < ROWS; ++r) {
    const int h = h0 + r;
    const size_t i = (size_t)h * WW + w;
    const float res = xcin[i] + acc[r] * rcpcnt<A>(h, w);
    if constexpr (FINAL) {
      dh[i] = __float2half(res - aux[i]);
    } else {
      xcout[i] = res;
      tp[(h + PADT) * SW + (w + PADL)] = aux[i] - res;
    }
  }
}

// zero the pad frame of both staging buffers
__global__ __launch_bounds__(64) void zeropad(float* __restrict__ tp, float* __restrict__ bp) {
  float* buf = blockIdx.y ? bp : tp;
  const int row = blockIdx.x;
  float* r = buf + (size_t)row * SW;
  if (row < PADT || row >= PADT + HH) {
    for (int c = threadIdx.x; c < SW; c += 64) r[c] = 0.0f;
  } else if (threadIdx.x < PADL) {
    r[threadIdx.x] = 0.0f;
    r[PADL + WW + threadIdx.x] = 0.0f;
  }
}

// tp interior = y - X
__global__ __launch_bounds__(256) void sub2pad(const float* __restrict__ y,
                                               const float* __restrict__ X,
                                               float* __restrict__ tp) {
  const int i = blockIdx.x * 256 + threadIdx.x;
  const int h = i >> 11, w = i & (WW - 1);
  tp[(h + PADT) * SW + (w + PADL)] = y[i] - X[i];
}

// E[i] = (dh[i], dh[i+1]) ; thread handles 2 outputs -> one 8B store
__global__ __launch_bounds__(256) void pack2(const __half* __restrict__ dh,
                                             uint2* __restrict__ E, int n2) {
  const int i = blockIdx.x * 256 + threadIdx.x;   // pair index
  const __half2 a = *(const __half2*)(dh + 2 * i);
  const __half nxt = (2 * i + 2 < 2 * n2) ? dh[2 * i + 2] : __low2half(a);
  union { __half2 h2[2]; uint2 u; } o;
  o.h2[0] = a;                                    // (dh[2i], dh[2i+1])
  o.h2[1] = __halves2half2(__high2half(a), nxt);  // (dh[2i+1], dh[2i+2])
  E[i] = o.u;
}

__device__ __forceinline__ float reflectf(float x, int size) {
  const float span = (float)(size - 1);
  const float ax = fabsf(x);
  const float extra = fmodf(ax, span);
  const float flips = floorf(ax / span);
  float r = (fmodf(flips, 2.0f) == 0.0f) ? extra : (span - extra);
  return fminf(fmaxf(r, 0.0f), span);
}

__global__ __launch_bounds__(256) void gather_k(const __half2* __restrict__ E,
                                                const float2* __restrict__ coor,
                                                const float* __restrict__ hX,
                                                float* __restrict__ out) {
  const int i = blockIdx.x * 256 + threadIdx.x;
  const float2 c = coor[i];
  const float gx = reflectf((c.x + 1.0f) * 0.5f * (float)(WW - 1), WW);
  const float gy = reflectf((c.y + 1.0f) * 0.5f * (float)(HH - 1), HH);
  const float x0 = floorf(gx), y0 = floorf(gy);
  const float wx = gx - x0, wy = gy - y0;
  int xi0 = min(max((int)x0, 0), WW - 1);
  int yi0 = min(max((int)y0, 0), HH - 1);
  int yi1 = min(max((int)(y0 + 1.0f), 0), HH - 1);
  const __half2 pa = E[yi0 * WW + xi0];   // (v00, v01)
  const __half2 pb = E[yi1 * WW + xi0];   // (v10, v11)
  const float v00 = __low2float(pa), v01 = __high2float(pa);
  const float v10 = __low2float(pb), v11 = __high2float(pb);
  out[i] = v00 * (1.0f - wx) * (1.0f - wy) + v01 * wx * (1.0f - wy) +
           v10 * (1.0f - wx) * wy + v11 * wx * wy + hX[i];
}

extern "C" void kernel_launch(void* const* d_in, const int* in_sizes, int n_in,
                              void* d_out, int out_size, void* d_ws, size_t ws_size,
                              hipStream_t stream) {
  const float* X    = (const float*)d_in[0];
  const float* y    = (const float*)d_in[1];
  const float* hX   = (const float*)d_in[2];
  const float* coor = (const float*)d_in[3];
  float* out = (float*)d_out;

  float*  tp = (float*)d_ws;             // padded t, 17.3 MB
  float*  bp = tp + PadElems;            // padded b, 17.3 MB
  __half* dh = (__half*)(bp + PadElems); // fp16 D,    8.4 MB
  uint2*  E  = (uint2*)tp;               // paired D, 16.8 MB — aliases tp (dead after last passA)
  float*  Xc = out;                      // Xc lives in d_out until gather rewrites it

  const int n = HH * WW;
  dim3 fgrd(WW / 256, HH / ROWS, 1);

  zeropad<<<dim3(PROWS, 2, 1), 64, 0, stream>>>(tp, bp);
  sub2pad<<<n / 256, 256, 0, stream>>>(y, X, tp);

  // iteration 0: -10deg  (Xc starts as X)
  passA<0><<<fgrd, 256, 0, stream>>>(tp, bp);
  passB<0, false><<<fgrd, 256, 0, stream>>>(bp, X, y, Xc, tp, nullptr);
  // iteration 1: 0deg
  passA<1><<<fgrd, 256, 0, stream>>>(tp, bp);
  passB<1, false><<<fgrd, 256, 0, stream>>>(bp, Xc, y, Xc, tp, nullptr);
  // iteration 2: +10deg  (emit D = Xc - X as fp16)
  passA<2><<<fgrd, 256, 0, stream>>>(tp, bp);
  passB<2, true><<<fgrd, 256, 0, stream>>>(bp, Xc, X, nullptr, nullptr, dh);

  pack2<<<(n / 2) / 256, 256, 0, stream>>>(dh, E, n / 2);
  gather_k<<<n / 256, 256, 0, stream>>>((const __half2*)E, (const float2*)coor, hX, out);
}

// Round 5
// 218.894 us; speedup vs baseline: 1.9510x; 1.9510x over previous
//
#include <hip/hip_runtime.h>
#include <hip/hip_fp16.h>

static constexpr int HH = 2048;
static constexpr int WW = 2048;
static constexpr int PADT = 24;   // top/bottom pad rows
static constexpr int PADL = 8;    // left/right pad cols
static constexpr int SW   = WW + 2 * PADL;          // 2064 floats
static constexpr int PROWS = HH + 2 * PADT;         // 2096 rows
static constexpr size_t PadElems = (size_t)PROWS * SW;
static constexpr int ROWS = 16;   // output rows per thread in filter kernels

// segment tables for +10 deg: lval(d)=round(d*tan(10deg)), runs of constant offset
__device__ constexpr int CS[9] = {-24,-19,-14,-8,-2, 3, 9,15,20};
__device__ constexpr int CE[9] = {-20,-15, -9,-3, 2, 8,14,19,24};
__device__ constexpr int CO[9] = { -4, -3, -2,-1, 0, 1, 2, 3, 4};

// ---- one slanted segment: vertical run [SS,EE] at col offset OO ----
template<int SS, int EE, int OO>
__device__ __forceinline__ void seg_one(const float* __restrict__ tp, int h0, int w,
                                        float* __restrict__ acc) {
  constexpr int L = EE - SS + 1;        // 5 or 6
  const float* p = tp + (h0 + SS + PADT) * SW + (w + OO + PADL);
  float ring[L - 1];
  float s = 0.0f;
#pragma unroll
  for (int k = 0; k < L - 1; ++k) { float v = p[k * SW]; ring[k] = v; s += v; }
#pragma unroll
  for (int r = 0; r < ROWS; ++r) {
    float v = p[(L - 1 + r) * SW];
    acc[r] += s + v;
    s += v - ring[r % (L - 1)];
    ring[r % (L - 1)] = v;
  }
}

template<int SGN>   // +1 => +10deg, -1 => -10deg
__device__ __forceinline__ void filt_slant(const float* __restrict__ tp, int h0, int w,
                                           float* __restrict__ acc) {
  seg_one<-24, -20, -4 * SGN>(tp, h0, w, acc);
  seg_one<-19, -15, -3 * SGN>(tp, h0, w, acc);
  seg_one<-14,  -9, -2 * SGN>(tp, h0, w, acc);
  seg_one< -8,  -3, -1 * SGN>(tp, h0, w, acc);
  seg_one< -2,   2,  0      >(tp, h0, w, acc);
  seg_one<  3,   8,  1 * SGN>(tp, h0, w, acc);
  seg_one<  9,  14,  2 * SGN>(tp, h0, w, acc);
  seg_one< 15,  19,  3 * SGN>(tp, h0, w, acc);
  seg_one< 20,  24,  4 * SGN>(tp, h0, w, acc);
}

// A: 0 => -10deg, 1 => 0deg, 2 => +10deg
template<int A>
__device__ __forceinline__ void filtN(const float* __restrict__ tp, int h0, int w,
                                      float* __restrict__ acc) {
#pragma unroll
  for (int r = 0; r < ROWS; ++r) acc[r] = 0.0f;
  if constexpr (A == 1) {
    const float* p = tp + (h0 - 24 + PADT) * SW + (w + PADL);
    float s = 0.0f;
#pragma unroll
    for (int k = 0; k < 48; ++k) s += p[k * SW];
#pragma unroll
    for (int r = 0; r < ROWS; ++r) {
      float vin = p[(48 + r) * SW];
      acc[r] = s + vin;
      s += vin - p[r * SW];
    }
  } else if constexpr (A == 0) {
    filt_slant<-1>(tp, h0, w, acc);
  } else {
    filt_slant<+1>(tp, h0, w, acc);
  }
}

// analytic 1/N (N = in-bounds tap count of zero-padded conv)
template<int A>
__device__ __forceinline__ float rcpcnt(int h, int w) {
  if (h >= 24 && h <= 2023 && w >= 4 && w <= 2043) return 1.0f / 49.0f;
  int cnt = 0;
  if constexpr (A == 1) {
    cnt = min(h + 24, HH - 1) - max(h - 24, 0) + 1;
  } else {
    const int sgn = (A == 0) ? -1 : 1;
#pragma unroll
    for (int j = 0; j < 9; ++j) {
      const int ww = w + sgn * CO[j];
      const int ov = min(h + CE[j], HH - 1) - max(h + CS[j], 0) + 1;
      if (ww >= 0 && ww < WW && ov > 0) cnt += ov;
    }
  }
  return 1.0f / (float)cnt;
}

// ---- pass A: bp = filt(tp)/N ----
template<int A>
__global__ __launch_bounds__(256) void passA(const float* __restrict__ tp,
                                             float* __restrict__ bp) {
  const int w  = blockIdx.x * 256 + threadIdx.x;
  const int h0 = blockIdx.y * ROWS;
  float acc[ROWS];
  filtN<A>(tp, h0, w, acc);
#pragma unroll
  for (int r = 0; r < ROWS; ++r) {
    const int h = h0 + r;
    bp[(h + PADT) * SW + (w + PADL)] = acc[r] * rcpcnt<A>(h, w);
  }
}

// ---- pass B (mid): res = xcin + filt(bp)/N; xcout=res, tp=y-res ----
template<int A>
__global__ __launch_bounds__(256) void passB(const float* __restrict__ bp,
                                             const float* __restrict__ xcin,
                                             const float* __restrict__ y,
                                             float* __restrict__ xcout,
                                             float* __restrict__ tp) {
  const int w  = blockIdx.x * 256 + threadIdx.x;
  const int h0 = blockIdx.y * ROWS;
  float acc[ROWS];
  filtN<A>(bp, h0, w, acc);
#pragma unroll
  for (int r = 0; r < ROWS; ++r) {
    const int h = h0 + r;
    const size_t i = (size_t)h * WW + w;
    const float res = xcin[i] + acc[r] * rcpcnt<A>(h, w);
    xcout[i] = res;
    tp[(h + PADT) * SW + (w + PADL)] = y[i] - res;
  }
}

// ---- pass B (final): D = res - X, emitted row-pair-interleaved fp16:
// E2[s*WW + w] = half2(D[2s][w], D[2s+1][w]) ----
template<int A>
__global__ __launch_bounds__(256) void passBF(const float* __restrict__ bp,
                                              const float* __restrict__ xcin,
                                              const float* __restrict__ X,
                                              __half2* __restrict__ E2) {
  const int w  = blockIdx.x * 256 + threadIdx.x;
  const int h0 = blockIdx.y * ROWS;
  float acc[ROWS];
  filtN<A>(bp, h0, w, acc);
  float res[ROWS];
#pragma unroll
  for (int r = 0; r < ROWS; ++r) {
    const int h = h0 + r;
    const size_t i = (size_t)h * WW + w;
    res[r] = xcin[i] + acc[r] * rcpcnt<A>(h, w) - X[i];
  }
#pragma unroll
  for (int r2 = 0; r2 < ROWS / 2; ++r2) {
    const int s = (h0 >> 1) + r2;
    E2[(size_t)s * WW + w] = __halves2half2(__float2half(res[2 * r2]),
                                            __float2half(res[2 * r2 + 1]));
  }
}

// zero the pad frame of both staging buffers
__global__ __launch_bounds__(64) void zeropad(float* __restrict__ tp, float* __restrict__ bp) {
  float* buf = blockIdx.y ? bp : tp;
  const int row = blockIdx.x;
  float* r = buf + (size_t)row * SW;
  if (row < PADT || row >= PADT + HH) {
    for (int c = threadIdx.x; c < SW; c += 64) r[c] = 0.0f;
  } else if (threadIdx.x < PADL) {
    r[threadIdx.x] = 0.0f;
    r[PADL + WW + threadIdx.x] = 0.0f;
  }
}

// tp interior = y - X
__global__ __launch_bounds__(256) void sub2pad(const float* __restrict__ y,
                                               const float* __restrict__ X,
                                               float* __restrict__ tp) {
  const int i = blockIdx.x * 256 + threadIdx.x;
  const int h = i >> 11, w = i & (WW - 1);
  tp[(h + PADT) * SW + (w + PADL)] = y[i] - X[i];
}

__device__ __forceinline__ float reflectf(float x, int size) {
  const float span = (float)(size - 1);
  const float ax = fabsf(x);
  const float extra = fmodf(ax, span);
  const float flips = floorf(ax / span);
  float r = (fmodf(flips, 2.0f) == 0.0f) ? extra : (span - extra);
  return fminf(fmaxf(r, 0.0f), span);
}

__global__ __launch_bounds__(256) void gather_k(const __half2* __restrict__ E2,
                                                const unsigned long long* __restrict__ coorU,
                                                const float* __restrict__ hX,
                                                float* __restrict__ out) {
  const int i = blockIdx.x * 256 + threadIdx.x;
  const unsigned long long cu = __builtin_nontemporal_load(&coorU[i]);
  union { unsigned long long u; float f[2]; } cc; cc.u = cu;
  const float gx = reflectf((cc.f[0] + 1.0f) * 0.5f * (float)(WW - 1), WW);
  const float gy = reflectf((cc.f[1] + 1.0f) * 0.5f * (float)(HH - 1), HH);
  const float x0 = floorf(gx), y0 = floorf(gy);
  const float wx = gx - x0, wy = gy - y0;
  const int xi0 = min(max((int)x0, 0), WW - 1);
  const int xi1 = min(max((int)(x0 + 1.0f), 0), WW - 1);
  const int yi0 = min(max((int)y0, 0), HH - 1);
  const int yi1 = min(max((int)(y0 + 1.0f), 0), HH - 1);
  const int s0 = yi0 >> 1, s1 = yi1 >> 1;
  const __half2 a0 = E2[s0 * WW + xi0];   // rows (2s0, 2s0+1) at col xi0
  const __half2 a1 = E2[s0 * WW + xi1];
  const __half2 b0 = E2[s1 * WW + xi0];
  const __half2 b1 = E2[s1 * WW + xi1];
  const float v00 = (yi0 & 1) ? __high2float(a0) : __low2float(a0);
  const float v01 = (yi0 & 1) ? __high2float(a1) : __low2float(a1);
  const float v10 = (yi1 & 1) ? __high2float(b0) : __low2float(b0);
  const float v11 = (yi1 & 1) ? __high2float(b1) : __low2float(b1);
  const float hx = __builtin_nontemporal_load(&hX[i]);
  const float r = v00 * (1.0f - wx) * (1.0f - wy) + v01 * wx * (1.0f - wy) +
                  v10 * (1.0f - wx) * wy + v11 * wx * wy + hx;
  __builtin_nontemporal_store(r, &out[i]);
}

extern "C" void kernel_launch(void* const* d_in, const int* in_sizes, int n_in,
                              void* d_out, int out_size, void* d_ws, size_t ws_size,
                              hipStream_t stream) {
  const float* X    = (const float*)d_in[0];
  const float* y    = (const float*)d_in[1];
  const float* hX   = (const float*)d_in[2];
  const float* coor = (const float*)d_in[3];
  float* out = (float*)d_out;

  float*   tp = (float*)d_ws;              // padded t, 17.3 MB
  float*   bp = tp + PadElems;             // padded b, 17.3 MB
  __half2* E2 = (__half2*)(bp + PadElems); // row-pair fp16 D, 8.4 MB
  float*   Xc = out;                       // Xc lives in d_out until gather rewrites it

  const int n = HH * WW;
  dim3 fgrd(WW / 256, HH / ROWS, 1);

  zeropad<<<dim3(PROWS, 2, 1), 64, 0, stream>>>(tp, bp);
  sub2pad<<<n / 256, 256, 0, stream>>>(y, X, tp);

  // iteration 0: -10deg  (Xc starts as X)
  passA<0><<<fgrd, 256, 0, stream>>>(tp, bp);
  passB<0><<<fgrd, 256, 0, stream>>>(bp, X, y, Xc, tp);
  // iteration 1: 0deg
  passA<1><<<fgrd, 256, 0, stream>>>(tp, bp);
  passB<1><<<fgrd, 256, 0, stream>>>(bp, Xc, y, Xc, tp);
  // iteration 2: +10deg  (emit E2 = pair-interleaved fp16 of Xc - X)
  passA<2><<<fgrd, 256, 0, stream>>>(tp, bp);
  passBF<2><<<fgrd, 256, 0, stream>>>(bp, Xc, X, E2);

  gather_k<<<n / 256, 256, 0, stream>>>(E2, (const unsigned long long*)coor, hX, out);
}